// Round 1
// baseline (197.497 us; speedup 1.0000x reference)
//
#include <hip/hip_runtime.h>
#include <math.h>

#define NV 3
#define NC 32
#define HS 256
#define WS 256
#define HT 128
#define WT 128
#define ND 48
#define NPIX (HT*WT)            // 16384
#define FEAT_T_ELEMS (NV*HS*WS*NC)  // 6291456 floats

// -------------------------------------------------------------------------
// Kernel 0: compute per-view 3x4 projection matrices
// proj_v = (Ks_v @ Ev[:3,:]) @ inv( [[Kt@Et[:3,:]],[0,0,0,1]] )
// -------------------------------------------------------------------------
__global__ void setup_proj(const float* __restrict__ src_exts,
                           const float* __restrict__ src_ints,
                           const float* __restrict__ tar_exts,
                           const float* __restrict__ tar_ints,
                           float* __restrict__ proj_out) {
    if (threadIdx.x != 0 || blockIdx.x != 0) return;
    float Kt[9], Et[16];
    for (int i = 0; i < 9;  i++) Kt[i] = tar_ints[i];
    for (int i = 0; i < 16; i++) Et[i] = tar_exts[i];
    // T = Kt @ Et[:3,:]  (3x4)
    float T[12];
    for (int r = 0; r < 3; r++)
        for (int col = 0; col < 4; col++) {
            float s = 0.f;
            for (int k = 0; k < 3; k++) s += Kt[r*3+k] * Et[k*4+col];
            T[r*4+col] = s;
        }
    // tar_proj = [[T],[0,0,0,1]]; inverse via 3x3 adjugate (bottom row exact)
    float M[9]  = {T[0],T[1],T[2], T[4],T[5],T[6], T[8],T[9],T[10]};
    float tv[3] = {T[3],T[7],T[11]};
    float det = M[0]*(M[4]*M[8]-M[5]*M[7])
              - M[1]*(M[3]*M[8]-M[5]*M[6])
              + M[2]*(M[3]*M[7]-M[4]*M[6]);
    float id = 1.0f/det;
    float Mi[9];
    Mi[0] =  (M[4]*M[8]-M[5]*M[7])*id;
    Mi[1] = -(M[1]*M[8]-M[2]*M[7])*id;
    Mi[2] =  (M[1]*M[5]-M[2]*M[4])*id;
    Mi[3] = -(M[3]*M[8]-M[5]*M[6])*id;
    Mi[4] =  (M[0]*M[8]-M[2]*M[6])*id;
    Mi[5] = -(M[0]*M[5]-M[2]*M[3])*id;
    Mi[6] =  (M[3]*M[7]-M[4]*M[6])*id;
    Mi[7] = -(M[0]*M[7]-M[1]*M[6])*id;
    Mi[8] =  (M[0]*M[4]-M[1]*M[3])*id;
    float mt[3];
    for (int r = 0; r < 3; r++)
        mt[r] = -(Mi[r*3+0]*tv[0] + Mi[r*3+1]*tv[1] + Mi[r*3+2]*tv[2]);
    float inv4[16] = {Mi[0],Mi[1],Mi[2],mt[0],
                      Mi[3],Mi[4],Mi[5],mt[1],
                      Mi[6],Mi[7],Mi[8],mt[2],
                      0.f,0.f,0.f,1.f};
    for (int v = 0; v < NV; v++) {
        const float* Ks = src_ints + v*9;
        const float* Ev = src_exts + v*16;
        float P34[12];
        for (int r = 0; r < 3; r++)
            for (int col = 0; col < 4; col++) {
                float s = 0.f;
                for (int k = 0; k < 3; k++) s += Ks[r*3+k] * Ev[k*4+col];
                P34[r*4+col] = s;
            }
        for (int r = 0; r < 3; r++)
            for (int col = 0; col < 4; col++) {
                float s = 0.f;
                for (int k = 0; k < 4; k++) s += P34[r*4+k] * inv4[k*4+col];
                proj_out[v*12 + r*4 + col] = s;
            }
    }
}

// -------------------------------------------------------------------------
// Kernel 1: transpose (V,C,Hs,Ws) -> (V,Hs,Ws,C) so channels are contiguous
// One block per (v,y) row. LDS tile transpose, pad 33 to dodge bank conflicts.
// -------------------------------------------------------------------------
__global__ __launch_bounds__(256) void transpose_feat(
        const float* __restrict__ src, float* __restrict__ dst) {
    __shared__ float tile[WS*33];   // 33.8 KB
    int vy = blockIdx.x;
    int v = vy / HS, y = vy % HS;
    int tid = threadIdx.x;          // 256 threads: tid = x for loads
    const float* in = src + (size_t)v*NC*HS*WS + (size_t)y*WS;
    #pragma unroll 4
    for (int c = 0; c < NC; c++) {
        tile[tid*33 + c] = in[(size_t)c*HS*WS + tid];
    }
    __syncthreads();
    float* out = dst + (size_t)(v*HS + y)*WS*NC;
    int c = tid & 31, x0 = tid >> 5;
    #pragma unroll 4
    for (int it = 0; it < 32; it++) {
        int x = it*8 + x0;
        out[x*NC + c] = tile[x*33 + c];
    }
}

// -------------------------------------------------------------------------
// Kernel 2: fused plane-sweep + variance cost + softmax + depth/CI.
// Wave = 2 pixels x 32 channels. Lane: c = lane&31 (channel),
// half = lane>>5 (which pixel). Per (depth,view): 4 coalesced tap loads.
// Costs land 2-per-lane (48 depths over 32 lanes); in-wave softmax.
// -------------------------------------------------------------------------
__global__ __launch_bounds__(256) void depth_main(
        const float* __restrict__ featT,
        const float* __restrict__ proj,
        const float* __restrict__ near_far,
        float* __restrict__ out) {
    const int tid  = threadIdx.x;
    const int wave = tid >> 6;
    const int lane = tid & 63;
    const int hf   = lane >> 5;      // pixel index within wave
    const int c    = lane & 31;      // channel

    const int pix = (blockIdx.x * 4 + wave) * 2 + hf;
    const int px  = pix & (WT - 1);
    const int py  = pix >> 7;

    const float cx = px + 0.5f, cy = py + 0.5f;

    float rx[NV], ry[NV], rz[NV], tx[NV], ty[NV], tz[NV];
    #pragma unroll
    for (int v = 0; v < NV; v++) {
        const float* P = proj + v*12;
        rx[v] = P[0]*cx + P[1]*cy + P[2];  tx[v] = P[3];
        ry[v] = P[4]*cx + P[5]*cy + P[6];  ty[v] = P[7];
        rz[v] = P[8]*cx + P[9]*cy + P[10]; tz[v] = P[11];
    }

    const float nearv = near_far[pix];
    const float farv  = near_far[NPIX + pix];
    const float step  = (farv - nearv) * (1.0f/(ND-1));

    const float BIG = 1.0e30f;
    float clo = BIG, chi = BIG;      // cost slots: d = c and d = c+32

    for (int d = 0; d < ND; d++) {
        const float dv = nearv + step * d;
        float a = 0.0f, m = 0.0f;
        #pragma unroll
        for (int v = 0; v < NV; v++) {
            float pxx = rx[v]*dv + tx[v];
            float pyy = ry[v]*dv + ty[v];
            float pzz = rz[v]*dv + tz[v];
            float z    = fmaxf(pzz, 1e-6f);
            float invz = 1.0f / z;
            float sx = fminf(fmaxf(pxx*invz - 0.5f, -1e6f), 1e6f);
            float sy = fminf(fmaxf(pyy*invz - 0.5f, -1e6f), 1e6f);
            float x0f = floorf(sx), y0f = floorf(sy);
            float wx = sx - x0f, wy = sy - y0f;
            int x0 = (int)x0f, y0 = (int)y0f;
            int x1 = x0 + 1,  y1 = y0 + 1;
            float ex0 = (x0 >= 0 && x0 < WS) ? (1.0f - wx) : 0.0f;
            float ex1 = (x1 >= 0 && x1 < WS) ? wx          : 0.0f;
            float ey0 = (y0 >= 0 && y0 < HS) ? (1.0f - wy) : 0.0f;
            float ey1 = (y1 >= 0 && y1 < HS) ? wy          : 0.0f;
            int cx0 = min(max(x0, 0), WS-1), cx1 = min(max(x1, 0), WS-1);
            int cy0 = min(max(y0, 0), HS-1), cy1 = min(max(y1, 0), HS-1);
            int b0 = ((v*HS + cy0)*WS)*NC;
            int b1 = ((v*HS + cy1)*WS)*NC;
            float f00 = featT[b0 + cx0*NC + c];
            float f01 = featT[b0 + cx1*NC + c];
            float f10 = featT[b1 + cx0*NC + c];
            float f11 = featT[b1 + cx1*NC + c];
            float val = ey0*(ex0*f00 + ex1*f01) + ey1*(ex0*f10 + ex1*f11);
            a += val*val;
            m += val;
        }
        float m2 = m*m;
        #pragma unroll
        for (int s = 1; s < 32; s <<= 1) {
            a  += __shfl_xor(a,  s, 64);
            m2 += __shfl_xor(m2, s, 64);
        }
        // var over views, mean over channels
        float cost = (a*(1.0f/3.0f) - m2*(1.0f/9.0f)) * (1.0f/32.0f);
        if (d < 32) { if (c == d)      clo = cost; }
        else        { if (c == d - 32) chi = cost; }
    }

    // in-wave softmax over 48 depths (2 slots per lane), per 32-lane half
    float n0 = -clo, n1 = -chi;          // padding slots: -1e30 -> exp ~ 0
    float mx = fmaxf(n0, n1);
    #pragma unroll
    for (int s = 1; s < 32; s <<= 1) mx = fmaxf(mx, __shfl_xor(mx, s, 64));
    const float dv0 = nearv + step * c;
    const float dv1 = nearv + step * (c + 32);
    float e0 = __expf(n0 - mx);
    float e1 = __expf(n1 - mx);
    float s0 = e0 + e1;
    float s1 = e0*dv0 + e1*dv1;
    #pragma unroll
    for (int s = 1; s < 32; s <<= 1) {
        s0 += __shfl_xor(s0, s, 64);
        s1 += __shfl_xor(s1, s, 64);
    }
    float depth = s1 / s0;
    float q0 = dv0 - depth, q1 = dv1 - depth;
    float s2 = e0*q0*q0 + e1*q1*q1;
    #pragma unroll
    for (int s = 1; s < 32; s <<= 1) s2 += __shfl_xor(s2, s, 64);
    float var = s2 / s0;
    float hci = sqrtf(fmaxf(var, 1e-12f));
    if (c == 0) {
        out[pix]          = depth;
        out[NPIX + pix]   = fmaxf(depth - hci, nearv);
        out[2*NPIX + pix] = fminf(depth + hci, farv);
    }
}

// -------------------------------------------------------------------------
extern "C" void kernel_launch(void* const* d_in, const int* in_sizes, int n_in,
                              void* d_out, int out_size, void* d_ws, size_t ws_size,
                              hipStream_t stream) {
    const float* src_feat = (const float*)d_in[0];
    const float* src_exts = (const float*)d_in[1];
    const float* src_ints = (const float*)d_in[2];
    const float* tar_exts = (const float*)d_in[3];
    const float* tar_ints = (const float*)d_in[4];
    const float* near_far = (const float*)d_in[5];
    float* out   = (float*)d_out;
    float* featT = (float*)d_ws;                 // 25.2 MB transposed features
    float* proj  = featT + FEAT_T_ELEMS;         // 36 floats of projections

    hipLaunchKernelGGL(setup_proj, dim3(1), dim3(64), 0, stream,
                       src_exts, src_ints, tar_exts, tar_ints, proj);
    hipLaunchKernelGGL(transpose_feat, dim3(NV*HS), dim3(256), 0, stream,
                       src_feat, featT);
    hipLaunchKernelGGL(depth_main, dim3(NPIX/8), dim3(256), 0, stream,
                       featT, proj, near_far, out);
}

// Round 2
// 159.440 us; speedup vs baseline: 1.2387x; 1.2387x over previous
//
#include <hip/hip_runtime.h>
#include <math.h>

#define NV 3
#define NC 32
#define HS 256
#define WS 256
#define HT 128
#define WT 128
#define ND 48
#define NPIX (HT*WT)            // 16384
#define FEAT_T_ELEMS (NV*HS*WS*NC)  // 6291456 floats

// -------------------------------------------------------------------------
// Kernel 0: compute per-view 3x4 projection matrices
// -------------------------------------------------------------------------
__global__ void setup_proj(const float* __restrict__ src_exts,
                           const float* __restrict__ src_ints,
                           const float* __restrict__ tar_exts,
                           const float* __restrict__ tar_ints,
                           float* __restrict__ proj_out) {
    if (threadIdx.x != 0 || blockIdx.x != 0) return;
    float Kt[9], Et[16];
    for (int i = 0; i < 9;  i++) Kt[i] = tar_ints[i];
    for (int i = 0; i < 16; i++) Et[i] = tar_exts[i];
    float T[12];
    for (int r = 0; r < 3; r++)
        for (int col = 0; col < 4; col++) {
            float s = 0.f;
            for (int k = 0; k < 3; k++) s += Kt[r*3+k] * Et[k*4+col];
            T[r*4+col] = s;
        }
    float M[9]  = {T[0],T[1],T[2], T[4],T[5],T[6], T[8],T[9],T[10]};
    float tv[3] = {T[3],T[7],T[11]};
    float det = M[0]*(M[4]*M[8]-M[5]*M[7])
              - M[1]*(M[3]*M[8]-M[5]*M[6])
              + M[2]*(M[3]*M[7]-M[4]*M[6]);
    float id = 1.0f/det;
    float Mi[9];
    Mi[0] =  (M[4]*M[8]-M[5]*M[7])*id;
    Mi[1] = -(M[1]*M[8]-M[2]*M[7])*id;
    Mi[2] =  (M[1]*M[5]-M[2]*M[4])*id;
    Mi[3] = -(M[3]*M[8]-M[5]*M[6])*id;
    Mi[4] =  (M[0]*M[8]-M[2]*M[6])*id;
    Mi[5] = -(M[0]*M[5]-M[2]*M[3])*id;
    Mi[6] =  (M[3]*M[7]-M[4]*M[6])*id;
    Mi[7] = -(M[0]*M[7]-M[1]*M[6])*id;
    Mi[8] =  (M[0]*M[4]-M[1]*M[3])*id;
    float mt[3];
    for (int r = 0; r < 3; r++)
        mt[r] = -(Mi[r*3+0]*tv[0] + Mi[r*3+1]*tv[1] + Mi[r*3+2]*tv[2]);
    float inv4[16] = {Mi[0],Mi[1],Mi[2],mt[0],
                      Mi[3],Mi[4],Mi[5],mt[1],
                      Mi[6],Mi[7],Mi[8],mt[2],
                      0.f,0.f,0.f,1.f};
    for (int v = 0; v < NV; v++) {
        const float* Ks = src_ints + v*9;
        const float* Ev = src_exts + v*16;
        float P34[12];
        for (int r = 0; r < 3; r++)
            for (int col = 0; col < 4; col++) {
                float s = 0.f;
                for (int k = 0; k < 3; k++) s += Ks[r*3+k] * Ev[k*4+col];
                P34[r*4+col] = s;
            }
        for (int r = 0; r < 3; r++)
            for (int col = 0; col < 4; col++) {
                float s = 0.f;
                for (int k = 0; k < 4; k++) s += P34[r*4+k] * inv4[k*4+col];
                proj_out[v*12 + r*4 + col] = s;
            }
    }
}

// -------------------------------------------------------------------------
// Kernel 1: transpose (V,C,Hs,Ws) -> (V,Hs,Ws,C)
// -------------------------------------------------------------------------
__global__ __launch_bounds__(256) void transpose_feat(
        const float* __restrict__ src, float* __restrict__ dst) {
    __shared__ float tile[WS*33];
    int vy = blockIdx.x;
    int v = vy / HS, y = vy % HS;
    int tid = threadIdx.x;
    const float* in = src + (size_t)v*NC*HS*WS + (size_t)y*WS;
    #pragma unroll 4
    for (int c = 0; c < NC; c++) {
        tile[tid*33 + c] = in[(size_t)c*HS*WS + tid];
    }
    __syncthreads();
    float* out = dst + (size_t)(v*HS + y)*WS*NC;
    int c = tid & 31, x0 = tid >> 5;
    #pragma unroll 4
    for (int it = 0; it < 32; it++) {
        int x = it*8 + x0;
        out[x*NC + c] = tile[x*33 + c];
    }
}

// -------------------------------------------------------------------------
// Kernel 2: fused plane-sweep + variance cost + softmax + depth/CI.
// Wave = 8 pixels x 8 lanes; each lane owns 4 channels (one float4).
// lane = p*8 + q : p = pixel-in-wave, q = channel-quad.
// Per (depth,view): scalar projection math amortized over 8 pixels,
// 4 float4 tap loads per pixel-group, 3-step shfl reduce over 8 lanes.
// Costs staged in a tiny per-wave LDS array; in-wave softmax epilogue.
// -------------------------------------------------------------------------
__global__ __launch_bounds__(256) void depth_main(
        const float* __restrict__ featT,
        const float* __restrict__ proj,
        const float* __restrict__ near_far,
        float* __restrict__ out) {
    __shared__ float cost_lds[32][49];   // 32 pixels/block x 48 depths (+pad)

    const int tid  = threadIdx.x;
    const int wave = tid >> 6;
    const int lane = tid & 63;
    const int p    = lane >> 3;      // pixel within wave (0..7)
    const int q    = lane & 7;       // channel quad (0..7) -> channels 4q..4q+3

    const int slot = wave*8 + p;     // pixel slot within block (0..31)
    const int pix  = (blockIdx.x*4 + wave)*8 + p;
    const int px   = pix & (WT - 1);
    const int py   = pix >> 7;

    const float cx = px + 0.5f, cy = py + 0.5f;

    float rx[NV], ry[NV], rz[NV], tx[NV], ty[NV], tz[NV];
    #pragma unroll
    for (int v = 0; v < NV; v++) {
        const float* P = proj + v*12;
        rx[v] = P[0]*cx + P[1]*cy + P[2];  tx[v] = P[3];
        ry[v] = P[4]*cx + P[5]*cy + P[6];  ty[v] = P[7];
        rz[v] = P[8]*cx + P[9]*cy + P[10]; tz[v] = P[11];
    }

    const float nearv = near_far[pix];
    const float farv  = near_far[NPIX + pix];
    const float step  = (farv - nearv) * (1.0f/(ND-1));
    const int   coff  = q*4;         // channel offset within the 32

    float* cl = cost_lds[slot];

    #pragma unroll 2
    for (int d = 0; d < ND; d++) {
        const float dv = nearv + step * d;
        float ax = 0.f, ay = 0.f, az = 0.f, aw = 0.f;   // sum_v val^2 per ch
        float mx_ = 0.f, my_ = 0.f, mz_ = 0.f, mw_ = 0.f; // sum_v val per ch
        #pragma unroll
        for (int v = 0; v < NV; v++) {
            float pxx = rx[v]*dv + tx[v];
            float pyy = ry[v]*dv + ty[v];
            float pzz = rz[v]*dv + tz[v];
            float z    = fmaxf(pzz, 1e-6f);
            float invz = 1.0f / z;
            float sx = fminf(fmaxf(pxx*invz - 0.5f, -1e6f), 1e6f);
            float sy = fminf(fmaxf(pyy*invz - 0.5f, -1e6f), 1e6f);
            float x0f = floorf(sx), y0f = floorf(sy);
            float wx = sx - x0f, wy = sy - y0f;
            int x0 = (int)x0f, y0 = (int)y0f;
            int x1 = x0 + 1,  y1 = y0 + 1;
            float ex0 = (x0 >= 0 && x0 < WS) ? (1.0f - wx) : 0.0f;
            float ex1 = (x1 >= 0 && x1 < WS) ? wx          : 0.0f;
            float ey0 = (y0 >= 0 && y0 < HS) ? (1.0f - wy) : 0.0f;
            float ey1 = (y1 >= 0 && y1 < HS) ? wy          : 0.0f;
            int cx0 = min(max(x0, 0), WS-1), cx1 = min(max(x1, 0), WS-1);
            int cy0 = min(max(y0, 0), HS-1), cy1 = min(max(y1, 0), HS-1);
            const float4* r0 = (const float4*)(featT + (size_t)((v*HS + cy0)*WS)*NC);
            const float4* r1 = (const float4*)(featT + (size_t)((v*HS + cy1)*WS)*NC);
            float4 f00 = r0[cx0*(NC/4) + q];
            float4 f01 = r0[cx1*(NC/4) + q];
            float4 f10 = r1[cx0*(NC/4) + q];
            float4 f11 = r1[cx1*(NC/4) + q];
            float vx = ey0*(ex0*f00.x + ex1*f01.x) + ey1*(ex0*f10.x + ex1*f11.x);
            float vy = ey0*(ex0*f00.y + ex1*f01.y) + ey1*(ex0*f10.y + ex1*f11.y);
            float vz = ey0*(ex0*f00.z + ex1*f01.z) + ey1*(ex0*f10.z + ex1*f11.z);
            float vw = ey0*(ex0*f00.w + ex1*f01.w) + ey1*(ex0*f10.w + ex1*f11.w);
            ax += vx*vx; ay += vy*vy; az += vz*vz; aw += vw*vw;
            mx_ += vx;   my_ += vy;   mz_ += vz;   mw_ += vw;
        }
        float a  = (ax + ay) + (az + aw);
        float m2 = mx_*mx_ + my_*my_ + mz_*mz_ + mw_*mw_;
        #pragma unroll
        for (int s = 1; s < 8; s <<= 1) {
            a  += __shfl_xor(a,  s, 64);
            m2 += __shfl_xor(m2, s, 64);
        }
        float cost = (a*(1.0f/3.0f) - m2*(1.0f/9.0f)) * (1.0f/32.0f);
        if (q == 0) cl[d] = cost;
    }

    // ---- softmax over 48 depths: lane q holds depths q, q+8, ..., q+40 ----
    float n[6], dvs[6];
    #pragma unroll
    for (int j = 0; j < 6; j++) {
        n[j]   = -cl[q + 8*j];
        dvs[j] = nearv + step * (float)(q + 8*j);
    }
    float mx = n[0];
    #pragma unroll
    for (int j = 1; j < 6; j++) mx = fmaxf(mx, n[j]);
    #pragma unroll
    for (int s = 1; s < 8; s <<= 1) mx = fmaxf(mx, __shfl_xor(mx, s, 64));
    float e[6];
    float s0 = 0.f, s1 = 0.f;
    #pragma unroll
    for (int j = 0; j < 6; j++) {
        e[j] = __expf(n[j] - mx);
        s0 += e[j];
        s1 += e[j]*dvs[j];
    }
    #pragma unroll
    for (int s = 1; s < 8; s <<= 1) {
        s0 += __shfl_xor(s0, s, 64);
        s1 += __shfl_xor(s1, s, 64);
    }
    float depth = s1 / s0;
    float s2 = 0.f;
    #pragma unroll
    for (int j = 0; j < 6; j++) {
        float qd = dvs[j] - depth;
        s2 += e[j]*qd*qd;
    }
    #pragma unroll
    for (int s = 1; s < 8; s <<= 1) s2 += __shfl_xor(s2, s, 64);
    float var = s2 / s0;
    float hci = sqrtf(fmaxf(var, 1e-12f));
    if (q == 0) {
        out[pix]          = depth;
        out[NPIX + pix]   = fmaxf(depth - hci, nearv);
        out[2*NPIX + pix] = fminf(depth + hci, farv);
    }
}

// -------------------------------------------------------------------------
extern "C" void kernel_launch(void* const* d_in, const int* in_sizes, int n_in,
                              void* d_out, int out_size, void* d_ws, size_t ws_size,
                              hipStream_t stream) {
    const float* src_feat = (const float*)d_in[0];
    const float* src_exts = (const float*)d_in[1];
    const float* src_ints = (const float*)d_in[2];
    const float* tar_exts = (const float*)d_in[3];
    const float* tar_ints = (const float*)d_in[4];
    const float* near_far = (const float*)d_in[5];
    float* out   = (float*)d_out;
    float* featT = (float*)d_ws;
    float* proj  = featT + FEAT_T_ELEMS;

    hipLaunchKernelGGL(setup_proj, dim3(1), dim3(64), 0, stream,
                       src_exts, src_ints, tar_exts, tar_ints, proj);
    hipLaunchKernelGGL(transpose_feat, dim3(NV*HS), dim3(256), 0, stream,
                       src_feat, featT);
    // 16384 pixels / (4 waves * 8 px per wave) = 512 blocks
    hipLaunchKernelGGL(depth_main, dim3(NPIX/32), dim3(256), 0, stream,
                       featT, proj, near_far, out);
}

// Round 3
// 130.858 us; speedup vs baseline: 1.5092x; 1.2184x over previous
//
#include <hip/hip_runtime.h>
#include <math.h>

#define NV 3
#define NC 32
#define HS 256
#define WS 256
#define HT 128
#define WT 128
#define ND 48
#define NPIX (HT*WT)             // 16384
#define HSP 259                  // padded rows: y+1 for y in [-1, 257]
#define WSP 259
#define ROW4 (WSP*8)             // float4 per padded row = 2072
#define IMG4 (HSP*ROW4)          // float4 per padded view = 536648
#define FEAT_T_ELEMS (NV*IMG4*4) // floats
#define NB_INTERIOR 6144         // (3*256*256*8)/256 blocks
#define NBORDER_PIX (3*(3*WSP + 3*HS))   // 4635 border pixels
#define NBORDER_F4  (NBORDER_PIX*8)      // 37080 float4
#define NB_BORDER   145                   // ceil(37080/256)

// -------------------------------------------------------------------------
// Kernel A: (V,C,Hs,Ws) -> zero-padded (V,Hs+3,Ws+3,C) transpose, plus
// border zeroing and (in one thread) the 3x4 projection matrix setup.
// Interior: thread=(v,y,x,q): 4 strided scalar loads -> 1 float4 store
// (wave stores are contiguous 1 KiB). No LDS, no barrier.
// -------------------------------------------------------------------------
__global__ __launch_bounds__(256) void prep(
        const float* __restrict__ src, float* __restrict__ dstf,
        const float* __restrict__ src_exts,
        const float* __restrict__ src_ints,
        const float* __restrict__ tar_exts,
        const float* __restrict__ tar_ints,
        float* __restrict__ proj_out) {
    float4* dst = (float4*)dstf;
    int bid = blockIdx.x;
    if (bid < NB_INTERIOR) {
        int g = bid*256 + threadIdx.x;       // (v,y,x,q) packed
        int q = g & 7;
        int x = (g >> 3) & (WS-1);
        int y = (g >> 11) & (HS-1);
        int v = g >> 19;
        const float* sp = src + (((size_t)(v*NC + q*4))*HS + y)*WS + x;
        float a = sp[0];
        float b = sp[HS*WS];
        float c = sp[2*HS*WS];
        float d = sp[3*HS*WS];
        dst[(v*HSP + y+1)*WSP*8 + (x+1)*8 + q] = make_float4(a,b,c,d);
        return;
    }
    // border zeroing
    int t = (bid - NB_INTERIOR)*256 + threadIdx.x;
    if (t < NBORDER_F4) {
        int pixb = t >> 3, q = t & 7;
        int v = pixb / (NBORDER_PIX/3);
        int r = pixb - v*(NBORDER_PIX/3);    // 0..1544
        int y, x;
        if (r < 3*WSP) {                      // rows y=0,257,258 full width
            int band = r / WSP;
            y = (band == 0) ? 0 : (band == 1 ? 257 : 258);
            x = r - band*WSP;
        } else {                              // cols x=0,257,258, y=1..256
            int rr = r - 3*WSP;
            int band = rr >> 8;               // /256
            x = (band == 0) ? 0 : (band == 1 ? 257 : 258);
            y = 1 + (rr & 255);
        }
        dst[(v*HSP + y)*WSP*8 + x*8 + q] = make_float4(0.f,0.f,0.f,0.f);
    }
    // projection matrices: one thread, alongside border work
    if (bid == NB_INTERIOR && threadIdx.x == 0) {
        float Kt[9], Et[16];
        for (int i = 0; i < 9;  i++) Kt[i] = tar_ints[i];
        for (int i = 0; i < 16; i++) Et[i] = tar_exts[i];
        float T[12];
        for (int rI = 0; rI < 3; rI++)
            for (int col = 0; col < 4; col++) {
                float s = 0.f;
                for (int k = 0; k < 3; k++) s += Kt[rI*3+k] * Et[k*4+col];
                T[rI*4+col] = s;
            }
        float M[9]  = {T[0],T[1],T[2], T[4],T[5],T[6], T[8],T[9],T[10]};
        float tv[3] = {T[3],T[7],T[11]};
        float det = M[0]*(M[4]*M[8]-M[5]*M[7])
                  - M[1]*(M[3]*M[8]-M[5]*M[6])
                  + M[2]*(M[3]*M[7]-M[4]*M[6]);
        float id = 1.0f/det;
        float Mi[9];
        Mi[0] =  (M[4]*M[8]-M[5]*M[7])*id;
        Mi[1] = -(M[1]*M[8]-M[2]*M[7])*id;
        Mi[2] =  (M[1]*M[5]-M[2]*M[4])*id;
        Mi[3] = -(M[3]*M[8]-M[5]*M[6])*id;
        Mi[4] =  (M[0]*M[8]-M[2]*M[6])*id;
        Mi[5] = -(M[0]*M[5]-M[2]*M[3])*id;
        Mi[6] =  (M[3]*M[7]-M[4]*M[6])*id;
        Mi[7] = -(M[0]*M[7]-M[1]*M[6])*id;
        Mi[8] =  (M[0]*M[4]-M[1]*M[3])*id;
        float mt[3];
        for (int rI = 0; rI < 3; rI++)
            mt[rI] = -(Mi[rI*3+0]*tv[0] + Mi[rI*3+1]*tv[1] + Mi[rI*3+2]*tv[2]);
        float inv4[16] = {Mi[0],Mi[1],Mi[2],mt[0],
                          Mi[3],Mi[4],Mi[5],mt[1],
                          Mi[6],Mi[7],Mi[8],mt[2],
                          0.f,0.f,0.f,1.f};
        for (int v = 0; v < NV; v++) {
            const float* Ks = src_ints + v*9;
            const float* Ev = src_exts + v*16;
            float P34[12];
            for (int rI = 0; rI < 3; rI++)
                for (int col = 0; col < 4; col++) {
                    float s = 0.f;
                    for (int k = 0; k < 3; k++) s += Ks[rI*3+k] * Ev[k*4+col];
                    P34[rI*4+col] = s;
                }
            for (int rI = 0; rI < 3; rI++)
                for (int col = 0; col < 4; col++) {
                    float s = 0.f;
                    for (int k = 0; k < 4; k++) s += P34[rI*4+k] * inv4[k*4+col];
                    proj_out[v*12 + rI*4 + col] = s;
                }
        }
    }
}

// -------------------------------------------------------------------------
// Kernel B: fused plane-sweep + variance cost + softmax + depth/CI.
// Block = 8 pixels, 4 waves; wave w owns depths w*12..w*12+11 (depth split
// for 4x occupancy). Wave lane = p*8+q: p pixel (0..7), q channel-quad.
// Zero-padded featT: no validity compares, no index clamps.
// Costs meet in LDS [8][56] (2-way banks = free); wave 0 does softmax.
// -------------------------------------------------------------------------
__global__ __launch_bounds__(256, 6) void depth_main(
        const float4* __restrict__ featT,
        const float* __restrict__ proj,
        const float* __restrict__ near_far,
        float* __restrict__ out) {
    __shared__ float cl[8][56];

    const int tid  = threadIdx.x;
    const int w    = tid >> 6;       // wave -> depth slice
    const int lane = tid & 63;
    const int p    = lane >> 3;      // pixel within block (0..7)
    const int q    = lane & 7;       // channel quad

    const int pix = blockIdx.x*8 + p;
    const float cx = (pix & (WT-1)) + 0.5f;
    const float cy = (pix >> 7) + 0.5f;

    float rx[NV], ry[NV], rz[NV], tx[NV], ty[NV], tz[NV];
    #pragma unroll
    for (int v = 0; v < NV; v++) {
        const float* P = proj + v*12;
        rx[v] = P[0]*cx + P[1]*cy + P[2];  tx[v] = P[3];
        ry[v] = P[4]*cx + P[5]*cy + P[6];  ty[v] = P[7];
        rz[v] = P[8]*cx + P[9]*cy + P[10]; tz[v] = P[11];
    }

    const float nearv = near_far[pix];
    const float farv  = near_far[NPIX + pix];
    const float step  = (farv - nearv) * (1.0f/(ND-1));
    const float d0    = (float)(w*12);

    #pragma unroll 2
    for (int dd = 0; dd < 12; dd++) {
        const float dv = fmaf(step, d0 + (float)dd, nearv);
        float ax=0.f, ay=0.f, az=0.f, aw=0.f;
        float mxs=0.f, mys=0.f, mzs=0.f, mws=0.f;
        #pragma unroll
        for (int v = 0; v < NV; v++) {
            float pxx = fmaf(rx[v], dv, tx[v]);
            float pyy = fmaf(ry[v], dv, ty[v]);
            float pzz = fmaf(rz[v], dv, tz[v]);
            float z    = fmaxf(pzz, 1e-6f);
            float invz = 1.0f / z;
            float sx = fminf(fmaxf(fmaf(pxx, invz, -0.5f), -1.0f), 256.0f);
            float sy = fminf(fmaxf(fmaf(pyy, invz, -0.5f), -1.0f), 256.0f);
            float x0f = floorf(sx), y0f = floorf(sy);
            float wx = sx - x0f,   wy = sy - y0f;
            int xi = (int)x0f + 1;           // 0..257 (padded col of x0)
            int yi = (int)y0f + 1;           // 0..257 (padded row of y0)
            int r0 = v*IMG4 + yi*ROW4 + xi*8 + q;
            int r1 = r0 + ROW4;
            float4 f00 = featT[r0];
            float4 f01 = featT[r0 + 8];
            float4 f10 = featT[r1];
            float4 f11 = featT[r1 + 8];
            float w11 = wx*wy;
            float w10 = wy - w11;
            float w01 = wx - w11;
            float w00 = (1.0f - wx) - w10;
            float vx = f00.x*w00 + f01.x*w01 + f10.x*w10 + f11.x*w11;
            float vy = f00.y*w00 + f01.y*w01 + f10.y*w10 + f11.y*w11;
            float vz = f00.z*w00 + f01.z*w01 + f10.z*w10 + f11.z*w11;
            float vw = f00.w*w00 + f01.w*w01 + f10.w*w10 + f11.w*w11;
            ax = fmaf(vx,vx,ax); ay = fmaf(vy,vy,ay);
            az = fmaf(vz,vz,az); aw = fmaf(vw,vw,aw);
            mxs += vx; mys += vy; mzs += vz; mws += vw;
        }
        float a  = (ax + ay) + (az + aw);
        float m2 = mxs*mxs + mys*mys + mzs*mzs + mws*mws;
        #pragma unroll
        for (int s = 1; s < 8; s <<= 1) {
            a  += __shfl_xor(a,  s, 64);
            m2 += __shfl_xor(m2, s, 64);
        }
        float cost = (a*(1.0f/3.0f) - m2*(1.0f/9.0f)) * (1.0f/32.0f);
        if (q == 0) cl[p][w*12 + dd] = cost;
    }

    __syncthreads();
    if (w != 0) return;

    // softmax over 48 depths: lane q holds depths q, q+8, ..., q+40
    float n[6], dvs[6];
    #pragma unroll
    for (int j = 0; j < 6; j++) {
        n[j]   = -cl[p][q + 8*j];
        dvs[j] = fmaf(step, (float)(q + 8*j), nearv);
    }
    float mx = n[0];
    #pragma unroll
    for (int j = 1; j < 6; j++) mx = fmaxf(mx, n[j]);
    #pragma unroll
    for (int s = 1; s < 8; s <<= 1) mx = fmaxf(mx, __shfl_xor(mx, s, 64));
    float e[6];
    float s0 = 0.f, s1 = 0.f;
    #pragma unroll
    for (int j = 0; j < 6; j++) {
        e[j] = __expf(n[j] - mx);
        s0 += e[j];
        s1 = fmaf(e[j], dvs[j], s1);
    }
    #pragma unroll
    for (int s = 1; s < 8; s <<= 1) {
        s0 += __shfl_xor(s0, s, 64);
        s1 += __shfl_xor(s1, s, 64);
    }
    float depth = s1 / s0;
    float s2 = 0.f;
    #pragma unroll
    for (int j = 0; j < 6; j++) {
        float qd = dvs[j] - depth;
        s2 = fmaf(e[j]*qd, qd, s2);
    }
    #pragma unroll
    for (int s = 1; s < 8; s <<= 1) s2 += __shfl_xor(s2, s, 64);
    float var = s2 / s0;
    float hci = sqrtf(fmaxf(var, 1e-12f));
    if (q == 0) {
        out[pix]          = depth;
        out[NPIX + pix]   = fmaxf(depth - hci, nearv);
        out[2*NPIX + pix] = fminf(depth + hci, farv);
    }
}

// -------------------------------------------------------------------------
extern "C" void kernel_launch(void* const* d_in, const int* in_sizes, int n_in,
                              void* d_out, int out_size, void* d_ws, size_t ws_size,
                              hipStream_t stream) {
    const float* src_feat = (const float*)d_in[0];
    const float* src_exts = (const float*)d_in[1];
    const float* src_ints = (const float*)d_in[2];
    const float* tar_exts = (const float*)d_in[3];
    const float* tar_ints = (const float*)d_in[4];
    const float* near_far = (const float*)d_in[5];
    float* out   = (float*)d_out;
    float* featT = (float*)d_ws;                 // 25.8 MB padded transposed
    float* proj  = featT + FEAT_T_ELEMS;         // 36 floats

    hipLaunchKernelGGL(prep, dim3(NB_INTERIOR + NB_BORDER), dim3(256), 0, stream,
                       src_feat, featT, src_exts, src_ints, tar_exts, tar_ints, proj);
    hipLaunchKernelGGL(depth_main, dim3(NPIX/8), dim3(256), 0, stream,
                       (const float4*)featT, proj, near_far, out);
}

// Round 4
// 123.884 us; speedup vs baseline: 1.5942x; 1.0563x over previous
//
#include <hip/hip_runtime.h>
#include <math.h>

#define NV 3
#define NC 32
#define HS 256
#define WS 256
#define HT 128
#define WT 128
#define ND 48
#define NPIX (HT*WT)             // 16384
#define HSP 259                  // padded rows: y+1 for y in [-1, 257]
#define WSP 259
#define ROW4 (WSP*8)             // float4 per padded row = 2072
#define IMG4 (HSP*ROW4)          // float4 per padded view = 536648
#define FEAT_T_ELEMS (NV*IMG4*4) // floats
#define NB_INTERIOR (NV*HS)      // 768 blocks: one per (v,y)
#define NBORDER_PIX (3*(3*WSP + 3*HS))   // 4635 border pixels
#define NBORDER_F4  (NBORDER_PIX*8)      // 37080 float4
#define NB_BORDER   145                   // ceil(37080/256)

// ---- 8-lane (aligned group) cross-lane reductions via DPP (VALU pipe) ----
__device__ __forceinline__ float dpp_sum8(float x) {
    int v;
    v = __builtin_amdgcn_update_dpp(0, __float_as_int(x), 0xB1,  0xF, 0xF, true); // quad_perm xor1
    x += __int_as_float(v);
    v = __builtin_amdgcn_update_dpp(0, __float_as_int(x), 0x4E,  0xF, 0xF, true); // quad_perm xor2
    x += __int_as_float(v);
    v = __builtin_amdgcn_update_dpp(0, __float_as_int(x), 0x141, 0xF, 0xF, true); // row_half_mirror
    x += __int_as_float(v);
    return x;
}
__device__ __forceinline__ float dpp_max8(float x) {
    int v;
    v = __builtin_amdgcn_update_dpp(0, __float_as_int(x), 0xB1,  0xF, 0xF, true);
    x = fmaxf(x, __int_as_float(v));
    v = __builtin_amdgcn_update_dpp(0, __float_as_int(x), 0x4E,  0xF, 0xF, true);
    x = fmaxf(x, __int_as_float(v));
    v = __builtin_amdgcn_update_dpp(0, __float_as_int(x), 0x141, 0xF, 0xF, true);
    x = fmaxf(x, __int_as_float(v));
    return x;
}

// -------------------------------------------------------------------------
// Kernel A: (V,C,Hs,Ws) -> zero-padded (V,Hs+3,Ws+3,C) transpose + border
// zeroing + projection setup. Interior block = one (v,y) row. Lane =
// (q, x0): loads are 2x128B fully-used segments, stores fill L2 lines
// across the block's 4 waves. No LDS, no barrier.
// -------------------------------------------------------------------------
__global__ __launch_bounds__(256) void prep(
        const float* __restrict__ src, float* __restrict__ dstf,
        const float* __restrict__ src_exts,
        const float* __restrict__ src_ints,
        const float* __restrict__ tar_exts,
        const float* __restrict__ tar_ints,
        float* __restrict__ proj_out) {
    float4* dst = (float4*)dstf;
    int bid = blockIdx.x;
    if (bid < NB_INTERIOR) {
        int v  = bid >> 8;
        int y  = bid & 255;
        int x0 = threadIdx.x & 31;
        int q  = threadIdx.x >> 5;           // channel quad 0..7
        const float* in = src + ((size_t)(v*NC + q*4))*HS*WS + (size_t)y*WS;
        float4* drow = dst + (size_t)(v*HSP + y+1)*ROW4 + 8 + q;
        #pragma unroll
        for (int it = 0; it < 8; it++) {
            int x = it*32 + x0;
            float a = in[x];
            float b = in[HS*WS   + x];
            float c = in[2*HS*WS + x];
            float d = in[3*HS*WS + x];
            drow[x*8] = make_float4(a,b,c,d);
        }
        return;
    }
    // border zeroing
    int t = (bid - NB_INTERIOR)*256 + threadIdx.x;
    if (t < NBORDER_F4) {
        int pixb = t >> 3, q = t & 7;
        int v = pixb / (NBORDER_PIX/3);
        int r = pixb - v*(NBORDER_PIX/3);
        int y, x;
        if (r < 3*WSP) {                      // rows y=0,257,258 full width
            int band = r / WSP;
            y = (band == 0) ? 0 : (band == 1 ? 257 : 258);
            x = r - band*WSP;
        } else {                              // cols x=0,257,258, y=1..256
            int rr = r - 3*WSP;
            int band = rr >> 8;
            x = (band == 0) ? 0 : (band == 1 ? 257 : 258);
            y = 1 + (rr & 255);
        }
        dst[(v*HSP + y)*WSP*8 + x*8 + q] = make_float4(0.f,0.f,0.f,0.f);
    }
    // projection matrices: one thread, alongside border work
    if (bid == NB_INTERIOR && threadIdx.x == 0) {
        float Kt[9], Et[16];
        for (int i = 0; i < 9;  i++) Kt[i] = tar_ints[i];
        for (int i = 0; i < 16; i++) Et[i] = tar_exts[i];
        float T[12];
        for (int rI = 0; rI < 3; rI++)
            for (int col = 0; col < 4; col++) {
                float s = 0.f;
                for (int k = 0; k < 3; k++) s += Kt[rI*3+k] * Et[k*4+col];
                T[rI*4+col] = s;
            }
        float M[9]  = {T[0],T[1],T[2], T[4],T[5],T[6], T[8],T[9],T[10]};
        float tv[3] = {T[3],T[7],T[11]};
        float det = M[0]*(M[4]*M[8]-M[5]*M[7])
                  - M[1]*(M[3]*M[8]-M[5]*M[6])
                  + M[2]*(M[3]*M[7]-M[4]*M[6]);
        float id = 1.0f/det;
        float Mi[9];
        Mi[0] =  (M[4]*M[8]-M[5]*M[7])*id;
        Mi[1] = -(M[1]*M[8]-M[2]*M[7])*id;
        Mi[2] =  (M[1]*M[5]-M[2]*M[4])*id;
        Mi[3] = -(M[3]*M[8]-M[5]*M[6])*id;
        Mi[4] =  (M[0]*M[8]-M[2]*M[6])*id;
        Mi[5] = -(M[0]*M[5]-M[2]*M[3])*id;
        Mi[6] =  (M[3]*M[7]-M[4]*M[6])*id;
        Mi[7] = -(M[0]*M[7]-M[1]*M[6])*id;
        Mi[8] =  (M[0]*M[4]-M[1]*M[3])*id;
        float mt[3];
        for (int rI = 0; rI < 3; rI++)
            mt[rI] = -(Mi[rI*3+0]*tv[0] + Mi[rI*3+1]*tv[1] + Mi[rI*3+2]*tv[2]);
        float inv4[16] = {Mi[0],Mi[1],Mi[2],mt[0],
                          Mi[3],Mi[4],Mi[5],mt[1],
                          Mi[6],Mi[7],Mi[8],mt[2],
                          0.f,0.f,0.f,1.f};
        for (int v = 0; v < NV; v++) {
            const float* Ks = src_ints + v*9;
            const float* Ev = src_exts + v*16;
            float P34[12];
            for (int rI = 0; rI < 3; rI++)
                for (int col = 0; col < 4; col++) {
                    float s = 0.f;
                    for (int k = 0; k < 3; k++) s += Ks[rI*3+k] * Ev[k*4+col];
                    P34[rI*4+col] = s;
                }
            for (int rI = 0; rI < 3; rI++)
                for (int col = 0; col < 4; col++) {
                    float s = 0.f;
                    for (int k = 0; k < 4; k++) s += P34[rI*4+k] * inv4[k*4+col];
                    proj_out[v*12 + rI*4 + col] = s;
                }
        }
    }
}

// -------------------------------------------------------------------------
// Kernel B: fused plane-sweep + variance cost + softmax + depth/CI.
// Block = 8 pixels, 4 waves; wave w owns 12 depths. Lane = p*8+q.
// XCD-swizzled blockIdx: each XCD covers 16 contiguous target rows so its
// source footprint (~4-5MB) lives in its own 4MiB L2.
// DPP reductions (VALU pipe) instead of ds_swizzle shuffles.
// -------------------------------------------------------------------------
__global__ __launch_bounds__(256, 6) void depth_main(
        const float4* __restrict__ featT,
        const float* __restrict__ proj,
        const float* __restrict__ near_far,
        float* __restrict__ out) {
    __shared__ float cl[8][56];

    const int tid  = threadIdx.x;
    const int w    = tid >> 6;       // wave -> depth slice
    const int lane = tid & 63;
    const int p    = lane >> 3;      // pixel within block (0..7)
    const int q    = lane & 7;       // channel quad

    // XCD swizzle: 2048 blocks, 8 XCDs -> XCD k owns logical [k*256,k*256+256)
    const int lb  = ((blockIdx.x & 7) << 8) | (blockIdx.x >> 3);
    const int pix = lb*8 + p;
    const float cx = (pix & (WT-1)) + 0.5f;
    const float cy = (pix >> 7) + 0.5f;

    float rx[NV], ry[NV], rz[NV], tx[NV], ty[NV], tz[NV];
    #pragma unroll
    for (int v = 0; v < NV; v++) {
        const float* P = proj + v*12;
        rx[v] = P[0]*cx + P[1]*cy + P[2];  tx[v] = P[3];
        ry[v] = P[4]*cx + P[5]*cy + P[6];  ty[v] = P[7];
        rz[v] = P[8]*cx + P[9]*cy + P[10]; tz[v] = P[11];
    }

    const float nearv = near_far[pix];
    const float farv  = near_far[NPIX + pix];
    const float step  = (farv - nearv) * (1.0f/(ND-1));
    const float d0    = (float)(w*12);

    const float4* base0 = featT + q;      // + v*IMG4 + yi*ROW4 + xi*8

    #pragma unroll 2
    for (int dd = 0; dd < 12; dd++) {
        const float dv = fmaf(step, d0 + (float)dd, nearv);
        float ax=0.f, ay=0.f, az=0.f, aw=0.f;
        float mxs=0.f, mys=0.f, mzs=0.f, mws=0.f;
        #pragma unroll
        for (int v = 0; v < NV; v++) {
            float pxx = fmaf(rx[v], dv, tx[v]);
            float pyy = fmaf(ry[v], dv, ty[v]);
            float pzz = fmaf(rz[v], dv, tz[v]);
            float z    = fmaxf(pzz, 1e-6f);
            float invz = 1.0f / z;
            float sx = fminf(fmaxf(fmaf(pxx, invz, -0.5f), -1.0f), 256.0f);
            float sy = fminf(fmaxf(fmaf(pyy, invz, -0.5f), -1.0f), 256.0f);
            float x0f = floorf(sx), y0f = floorf(sy);
            float wx = sx - x0f,   wy = sy - y0f;
            int xi = (int)x0f + 1;           // 0..257
            int yi = (int)y0f + 1;           // 0..257
            int r0 = v*IMG4 + yi*ROW4 + xi*8;
            int r1 = r0 + ROW4;
            float4 f00 = base0[r0];
            float4 f01 = base0[r0 + 8];
            float4 f10 = base0[r1];
            float4 f11 = base0[r1 + 8];
            float w11 = wx*wy;
            float w10 = wy - w11;
            float w01 = wx - w11;
            float w00 = (1.0f - wx) - w10;
            float vx = f00.x*w00 + f01.x*w01 + f10.x*w10 + f11.x*w11;
            float vy = f00.y*w00 + f01.y*w01 + f10.y*w10 + f11.y*w11;
            float vz = f00.z*w00 + f01.z*w01 + f10.z*w10 + f11.z*w11;
            float vw = f00.w*w00 + f01.w*w01 + f10.w*w10 + f11.w*w11;
            ax = fmaf(vx,vx,ax); ay = fmaf(vy,vy,ay);
            az = fmaf(vz,vz,az); aw = fmaf(vw,vw,aw);
            mxs += vx; mys += vy; mzs += vz; mws += vw;
        }
        float a  = dpp_sum8((ax + ay) + (az + aw));
        float m2 = dpp_sum8(mxs*mxs + mys*mys + mzs*mzs + mws*mws);
        float cost = (a*(1.0f/3.0f) - m2*(1.0f/9.0f)) * (1.0f/32.0f);
        if (q == 0) cl[p][w*12 + dd] = cost;
    }

    __syncthreads();
    if (w != 0) return;

    // softmax over 48 depths: lane q holds depths q, q+8, ..., q+40
    float n[6], dvs[6];
    #pragma unroll
    for (int j = 0; j < 6; j++) {
        n[j]   = -cl[p][q + 8*j];
        dvs[j] = fmaf(step, (float)(q + 8*j), nearv);
    }
    float mx = n[0];
    #pragma unroll
    for (int j = 1; j < 6; j++) mx = fmaxf(mx, n[j]);
    mx = dpp_max8(mx);
    float e[6];
    float s0 = 0.f, s1 = 0.f;
    #pragma unroll
    for (int j = 0; j < 6; j++) {
        e[j] = __expf(n[j] - mx);
        s0 += e[j];
        s1 = fmaf(e[j], dvs[j], s1);
    }
    s0 = dpp_sum8(s0);
    s1 = dpp_sum8(s1);
    float depth = s1 / s0;
    float s2 = 0.f;
    #pragma unroll
    for (int j = 0; j < 6; j++) {
        float qd = dvs[j] - depth;
        s2 = fmaf(e[j]*qd, qd, s2);
    }
    s2 = dpp_sum8(s2);
    float var = s2 / s0;
    float hci = sqrtf(fmaxf(var, 1e-12f));
    if (q == 0) {
        out[pix]          = depth;
        out[NPIX + pix]   = fmaxf(depth - hci, nearv);
        out[2*NPIX + pix] = fminf(depth + hci, farv);
    }
}

// -------------------------------------------------------------------------
extern "C" void kernel_launch(void* const* d_in, const int* in_sizes, int n_in,
                              void* d_out, int out_size, void* d_ws, size_t ws_size,
                              hipStream_t stream) {
    const float* src_feat = (const float*)d_in[0];
    const float* src_exts = (const float*)d_in[1];
    const float* src_ints = (const float*)d_in[2];
    const float* tar_exts = (const float*)d_in[3];
    const float* tar_ints = (const float*)d_in[4];
    const float* near_far = (const float*)d_in[5];
    float* out   = (float*)d_out;
    float* featT = (float*)d_ws;                 // 25.8 MB padded transposed
    float* proj  = featT + FEAT_T_ELEMS;         // 36 floats

    hipLaunchKernelGGL(prep, dim3(NB_INTERIOR + NB_BORDER), dim3(256), 0, stream,
                       src_feat, featT, src_exts, src_ints, tar_exts, tar_ints, proj);
    hipLaunchKernelGGL(depth_main, dim3(NPIX/8), dim3(256), 0, stream,
                       (const float4*)featT, proj, near_far, out);
}